// Round 1
// baseline (860.443 us; speedup 1.0000x reference)
//
#include <hip/hip_runtime.h>
#include <math.h>

#define NN 20000
#define EE 320000
#define FXX 256
#define FWW 128
#define FHH 128
#define NH 4

// ---------------------------------------------------------------- GEMM
// C[M,128] = A[M,K] * B[K,128] for 5 batches: z<4 -> W[z] into Hout[z], z==4 -> R into Res.
__global__ __launch_bounds__(256) void gat_gemm(const float* __restrict__ A,
                                                const float* __restrict__ W,
                                                const float* __restrict__ R,
                                                float* __restrict__ Hout,
                                                float* __restrict__ Res,
                                                int M, int K)
{
    int z = blockIdx.z;
    const float* B = (z < 4) ? (W + (size_t)z * K * 128) : R;
    float*       C = (z < 4) ? (Hout + (size_t)z * M * 128) : Res;

    __shared__ float As[16][68];   // A tile transposed, padded for banks/alignment
    __shared__ float Bs[16][64];

    int tid = threadIdx.x;
    int tx = tid & 15, ty = tid >> 4;
    int row0 = blockIdx.x * 64, col0 = blockIdx.y * 64;

    int lam = tid >> 2, lak = (tid & 3) * 4;   // A loader: 64 rows x 16 k
    int lbk = tid >> 4, lbn = (tid & 15) * 4;  // B loader: 16 k x 64 cols

    float acc[4][4] = {};

    for (int kb = 0; kb < K; kb += 16) {
        float4 av = make_float4(0.f, 0.f, 0.f, 0.f);
        int arow = row0 + lam;
        if (arow < M) av = *(const float4*)(A + (size_t)arow * K + kb + lak);
        As[lak + 0][lam] = av.x;
        As[lak + 1][lam] = av.y;
        As[lak + 2][lam] = av.z;
        As[lak + 3][lam] = av.w;
        float4 bv = *(const float4*)(B + (size_t)(kb + lbk) * 128 + col0 + lbn);
        Bs[lbk][lbn + 0] = bv.x; Bs[lbk][lbn + 1] = bv.y;
        Bs[lbk][lbn + 2] = bv.z; Bs[lbk][lbn + 3] = bv.w;
        __syncthreads();
        #pragma unroll
        for (int k = 0; k < 16; ++k) {
            float a[4], b[4];
            #pragma unroll
            for (int i = 0; i < 4; ++i) a[i] = As[k][ty * 4 + i];
            #pragma unroll
            for (int j = 0; j < 4; ++j) b[j] = Bs[k][tx * 4 + j];
            #pragma unroll
            for (int i = 0; i < 4; ++i)
                #pragma unroll
                for (int j = 0; j < 4; ++j)
                    acc[i][j] += a[i] * b[j];
        }
        __syncthreads();
    }
    #pragma unroll
    for (int i = 0; i < 4; ++i) {
        int row = row0 + ty * 4 + i;
        if (row < M) {
            float4 v = make_float4(acc[i][0], acc[i][1], acc[i][2], acc[i][3]);
            *(float4*)(C + (size_t)row * 128 + col0 + tx * 4) = v;
        }
    }
}

// ---------------------------------------------------------------- attention scores s_src/s_dst
// one wave per node; lane covers 2 features via float2
__global__ __launch_bounds__(256) void s_kernel(const float* __restrict__ Hh,
                                                const float* __restrict__ avs,
                                                const float* __restrict__ avd,
                                                float* __restrict__ ssrc,
                                                float* __restrict__ sdst)
{
    int wid = threadIdx.x >> 6, lane = threadIdx.x & 63;
    int n = blockIdx.x * 4 + wid;
    if (n >= NN) return;
    #pragma unroll
    for (int h = 0; h < NH; ++h) {
        const float* hp = Hh + ((size_t)h * NN + n) * 128;
        float2 hv = *(const float2*)(hp + 2 * lane);
        float2 sv = *(const float2*)(avs + h * 128 + 2 * lane);
        float2 dv = *(const float2*)(avd + h * 128 + 2 * lane);
        float vs = hv.x * sv.x + hv.y * sv.y;
        float vd = hv.x * dv.x + hv.y * dv.y;
        #pragma unroll
        for (int o = 32; o; o >>= 1) { vs += __shfl_down(vs, o); vd += __shfl_down(vd, o); }
        if (lane == 0) { ssrc[n * 4 + h] = vs; sdst[n * 4 + h] = vd; }
    }
}

// ---------------------------------------------------------------- per-edge scores e = lrelu(s_src[src]+s_dst[dst])
__global__ __launch_bounds__(256) void edge_kernel(const int* __restrict__ src,
                                                   const int* __restrict__ dst,
                                                   const float* __restrict__ ssrc,
                                                   const float* __restrict__ sdst,
                                                   float* __restrict__ e)
{
    int i = blockIdx.x * blockDim.x + threadIdx.x;
    if (i >= EE) return;
    int s = src[i], d = dst[i];
    float4 a = *(const float4*)(ssrc + (size_t)s * 4);
    float4 b = *(const float4*)(sdst + (size_t)d * 4);
    float4 r;
    float t;
    t = a.x + b.x; r.x = t >= 0.f ? t : 0.2f * t;
    t = a.y + b.y; r.y = t >= 0.f ? t : 0.2f * t;
    t = a.z + b.z; r.z = t >= 0.f ? t : 0.2f * t;
    t = a.w + b.w; r.w = t >= 0.f ? t : 0.2f * t;
    *(float4*)(e + (size_t)i * 4) = r;
}

// ---------------------------------------------------------------- CSR build
__global__ __launch_bounds__(256) void hist_kernel(const int* __restrict__ src, int* __restrict__ cnt)
{
    int i = blockIdx.x * blockDim.x + threadIdx.x;
    if (i < EE) atomicAdd(&cnt[src[i]], 1);
}

__global__ __launch_bounds__(1024) void scan_kernel(const int* __restrict__ cnt, int* __restrict__ row_ptr)
{
    __shared__ int lds[1024];
    int t = threadIdx.x;
    const int CH = 20;  // 1024*20 >= NN
    int start = t * CH, end = start + CH; if (end > NN) end = NN;
    int sum = 0;
    if (start < NN) for (int i = start; i < end; ++i) sum += cnt[i];
    lds[t] = sum;
    __syncthreads();
    for (int o = 1; o < 1024; o <<= 1) {
        int v = (t >= o) ? lds[t - o] : 0;
        __syncthreads();
        lds[t] += v;
        __syncthreads();
    }
    int run = lds[t] - sum;  // exclusive base
    if (start < NN) for (int i = start; i < end; ++i) { row_ptr[i] = run; run += cnt[i]; }
    if (t == 1023) row_ptr[NN] = lds[1023];
}

__global__ __launch_bounds__(256) void scatter_kernel(const int* __restrict__ src,
                                                      const int* __restrict__ dst,
                                                      const int* __restrict__ row_ptr,
                                                      int* __restrict__ off,
                                                      int* __restrict__ csr_eid,
                                                      int* __restrict__ csr_dst)
{
    int i = blockIdx.x * blockDim.x + threadIdx.x;
    if (i >= EE) return;
    int s = src[i];
    int p = row_ptr[s] + atomicAdd(&off[s], 1);
    csr_eid[p] = i;
    csr_dst[p] = dst[i];
}

// ---------------------------------------------------------------- per-node softmax -> alpha (CSR order)
__global__ __launch_bounds__(256) void alpha_kernel(const float* __restrict__ e,
                                                    const int* __restrict__ row_ptr,
                                                    const int* __restrict__ csr_eid,
                                                    float* __restrict__ alpha)
{
    int wid = threadIdx.x >> 6, lane = threadIdx.x & 63;
    int n = blockIdx.x * 4 + wid;
    if (n >= NN) return;
    int r0 = row_ptr[n], r1 = row_ptr[n + 1];
    int deg = r1 - r0;
    if (deg == 0) return;

    float4 m = make_float4(-1e30f, -1e30f, -1e30f, -1e30f);
    for (int s = lane; s < deg; s += 64) {
        int eid = csr_eid[r0 + s];
        float4 ev = *(const float4*)(e + (size_t)eid * 4);
        m.x = fmaxf(m.x, ev.x); m.y = fmaxf(m.y, ev.y);
        m.z = fmaxf(m.z, ev.z); m.w = fmaxf(m.w, ev.w);
    }
    #pragma unroll
    for (int o = 32; o; o >>= 1) {
        m.x = fmaxf(m.x, __shfl_xor(m.x, o));
        m.y = fmaxf(m.y, __shfl_xor(m.y, o));
        m.z = fmaxf(m.z, __shfl_xor(m.z, o));
        m.w = fmaxf(m.w, __shfl_xor(m.w, o));
    }
    float4 den = make_float4(0.f, 0.f, 0.f, 0.f);
    for (int s = lane; s < deg; s += 64) {
        int eid = csr_eid[r0 + s];
        float4 ev = *(const float4*)(e + (size_t)eid * 4);
        den.x += expf(ev.x - m.x); den.y += expf(ev.y - m.y);
        den.z += expf(ev.z - m.z); den.w += expf(ev.w - m.w);
    }
    #pragma unroll
    for (int o = 32; o; o >>= 1) {
        den.x += __shfl_xor(den.x, o); den.y += __shfl_xor(den.y, o);
        den.z += __shfl_xor(den.z, o); den.w += __shfl_xor(den.w, o);
    }
    den.x += 1e-16f; den.y += 1e-16f; den.z += 1e-16f; den.w += 1e-16f;
    for (int s = lane; s < deg; s += 64) {
        int eid = csr_eid[r0 + s];
        float4 ev = *(const float4*)(e + (size_t)eid * 4);
        float4 o4;
        o4.x = expf(ev.x - m.x) / den.x;
        o4.y = expf(ev.y - m.y) / den.y;
        o4.z = expf(ev.z - m.z) / den.z;
        o4.w = expf(ev.w - m.w) / den.w;
        *(float4*)(alpha + (size_t)(r0 + s) * 4) = o4;
    }
}

// ---------------------------------------------------------------- aggregate + residual + ELU
// block per node, wave per head; lane covers 2 features
__global__ __launch_bounds__(256) void agg_kernel(const float* __restrict__ Hh,
                                                  const float* __restrict__ alpha,
                                                  const int* __restrict__ row_ptr,
                                                  const int* __restrict__ csr_dst,
                                                  const float* __restrict__ res,
                                                  float* __restrict__ xout)
{
    __shared__ float lds[NH][128];
    int n = blockIdx.x;
    int wid = threadIdx.x >> 6, lane = threadIdx.x & 63;
    int r0 = row_ptr[n], r1 = row_ptr[n + 1];
    const float* hbase = Hh + (size_t)wid * NN * 128;
    float2 acc = make_float2(0.f, 0.f);
    for (int s = r0; s < r1; ++s) {
        float w = alpha[(size_t)s * 4 + wid];
        int d = csr_dst[s];
        float2 hv = *(const float2*)(hbase + (size_t)d * 128 + 2 * lane);
        acc.x += w * hv.x;
        acc.y += w * hv.y;
    }
    lds[wid][2 * lane]     = acc.x;
    lds[wid][2 * lane + 1] = acc.y;
    __syncthreads();
    int t = threadIdx.x;
    if (t < 128) {
        float v = (lds[0][t] + lds[1][t] + lds[2][t] + lds[3][t]) * 0.25f
                  + res[(size_t)n * 128 + t];
        xout[(size_t)n * 128 + t] = v > 0.f ? v : expm1f(v);
    }
}

// ---------------------------------------------------------------- SE pooling: per-channel global mean (partial sums)
__global__ __launch_bounds__(256) void pool_reduce(const float* __restrict__ x1,
                                                   const float* __restrict__ x2,
                                                   const float* __restrict__ d1,
                                                   const float* __restrict__ d2,
                                                   float* __restrict__ sums)
{
    int c = blockIdx.y;
    const float* p = (c == 0) ? x1 : (c == 1) ? x2 : (c == 2) ? d1 : d2;
    const int total = NN * 128;
    float s = 0.f;
    for (int i = blockIdx.x * blockDim.x + threadIdx.x; i < total; i += gridDim.x * blockDim.x)
        s += p[i];
    #pragma unroll
    for (int o = 32; o; o >>= 1) s += __shfl_down(s, o);
    __shared__ float ls[4];
    if ((threadIdx.x & 63) == 0) ls[threadIdx.x >> 6] = s;
    __syncthreads();
    if (threadIdx.x == 0) atomicAdd(&sums[c], ls[0] + ls[1] + ls[2] + ls[3]);
}

// ---------------------------------------------------------------- SE MLP -> att[4]
__global__ void att_kernel(const float* __restrict__ sums,
                           const float* __restrict__ fc1w, const float* __restrict__ fc1b,
                           const float* __restrict__ fc2w, const float* __restrict__ fc2b,
                           float* __restrict__ att)
{
    if (threadIdx.x != 0 || blockIdx.x != 0) return;
    float avg[4];
    for (int c = 0; c < 4; ++c) avg[c] = sums[c] * (1.f / (NN * 128.f));
    float z[20];
    for (int j = 0; j < 20; ++j) {
        float v = fc1b[j];
        for (int c = 0; c < 4; ++c) v += avg[c] * fc1w[c * 20 + j];
        z[j] = v;
    }
    for (int c = 0; c < 4; ++c) {
        float v = fc2b[c];
        for (int j = 0; j < 20; ++j) v += z[j] * fc2w[j * 4 + c];
        att[c] = 1.f / (1.f + expf(-v));
    }
}

// ---------------------------------------------------------------- final: relu(att*x_c) 1x1 conv
__global__ __launch_bounds__(256) void final_kernel(const float* __restrict__ x1,
                                                    const float* __restrict__ x2,
                                                    const float* __restrict__ d1,
                                                    const float* __restrict__ d2,
                                                    const float* __restrict__ att,
                                                    const float* __restrict__ convw,
                                                    const float* __restrict__ convb,
                                                    float* __restrict__ out)
{
    int i = blockIdx.x * blockDim.x + threadIdx.x;
    if (i >= NN * 128) return;
    float a0 = att[0], a1 = att[1], a2 = att[2], a3 = att[3];
    float w0 = convw[0], w1 = convw[1], w2 = convw[2], w3 = convw[3];
    float v = convb[0];
    v += w0 * fmaxf(a0 * x1[i], 0.f);
    v += w1 * fmaxf(a1 * x2[i], 0.f);
    v += w2 * fmaxf(a2 * d1[i], 0.f);
    v += w3 * fmaxf(a3 * d2[i], 0.f);
    out[i] = v;
}

// ---------------------------------------------------------------- host
extern "C" void kernel_launch(void* const* d_in, const int* in_sizes, int n_in,
                              void* d_out, int out_size, void* d_ws, size_t ws_size,
                              hipStream_t stream)
{
    (void)in_sizes; (void)n_in; (void)out_size; (void)ws_size;
    const float* x    = (const float*)d_in[0];
    const float* dat  = (const float*)d_in[1];
    const float* W1   = (const float*)d_in[2];
    const float* a1s  = (const float*)d_in[3];
    const float* a1d  = (const float*)d_in[4];
    const float* R1   = (const float*)d_in[5];
    const float* W2   = (const float*)d_in[6];
    const float* a2s  = (const float*)d_in[7];
    const float* a2d  = (const float*)d_in[8];
    const float* R2   = (const float*)d_in[9];
    const float* Wd1  = (const float*)d_in[10];
    const float* ad1s = (const float*)d_in[11];
    const float* ad1d = (const float*)d_in[12];
    const float* Rd1  = (const float*)d_in[13];
    const float* Wd2  = (const float*)d_in[14];
    const float* ad2s = (const float*)d_in[15];
    const float* ad2d = (const float*)d_in[16];
    const float* Rd2  = (const float*)d_in[17];
    const float* fc1w = (const float*)d_in[18];
    const float* fc1b = (const float*)d_in[19];
    const float* fc2w = (const float*)d_in[20];
    const float* fc2b = (const float*)d_in[21];
    const float* convw= (const float*)d_in[22];
    const float* convb= (const float*)d_in[23];
    const int*   eidx = (const int*)d_in[24];
    const int* esrc = eidx;
    const int* edst = eidx + EE;
    float* out = (float*)d_out;

    char* base = (char*)d_ws;
    size_t woff = 0;
    auto alloc = [&](size_t bytes) -> void* {
        void* p = base + woff;
        woff = (woff + bytes + 255) & ~(size_t)255;
        return p;
    };
    float* Hbuf  = (float*)alloc((size_t)NH * NN * 128 * 4);
    float* Resb  = (float*)alloc((size_t)NN * 128 * 4);
    float* X1    = (float*)alloc((size_t)NN * 128 * 4);
    float* X2    = (float*)alloc((size_t)NN * 128 * 4);
    float* D1    = (float*)alloc((size_t)NN * 128 * 4);
    float* D2    = (float*)alloc((size_t)NN * 128 * 4);
    float* Ssrc  = (float*)alloc((size_t)NN * 4 * 4);
    float* Sdst  = (float*)alloc((size_t)NN * 4 * 4);
    float* Ebuf  = (float*)alloc((size_t)EE * 4 * 4);
    float* Albuf = (float*)alloc((size_t)EE * 4 * 4);
    int* RowPtr  = (int*)alloc((size_t)(NN + 1) * 4);
    int* Cnt     = (int*)alloc((size_t)NN * 4);
    int* Off     = (int*)alloc((size_t)NN * 4);
    int* CsrEid  = (int*)alloc((size_t)EE * 4);
    int* CsrDst  = (int*)alloc((size_t)EE * 4);
    float* Sums  = (float*)alloc(16);
    float* Att   = (float*)alloc(16);

    hipMemsetAsync(Cnt, 0, (size_t)NN * 4, stream);
    hipMemsetAsync(Off, 0, (size_t)NN * 4, stream);
    hist_kernel<<<(EE + 255) / 256, 256, 0, stream>>>(esrc, Cnt);
    scan_kernel<<<1, 1024, 0, stream>>>(Cnt, RowPtr);
    scatter_kernel<<<(EE + 255) / 256, 256, 0, stream>>>(esrc, edst, RowPtr, Off, CsrEid, CsrDst);

    auto layer = [&](const float* xin, int K, const float* W, const float* as_,
                     const float* ad_, const float* R, float* xout) {
        dim3 g((NN + 63) / 64, 2, 5);
        gat_gemm<<<g, 256, 0, stream>>>(xin, W, R, Hbuf, Resb, NN, K);
        s_kernel<<<(NN + 3) / 4, 256, 0, stream>>>(Hbuf, as_, ad_, Ssrc, Sdst);
        edge_kernel<<<(EE + 255) / 256, 256, 0, stream>>>(esrc, edst, Ssrc, Sdst, Ebuf);
        alpha_kernel<<<(NN + 3) / 4, 256, 0, stream>>>(Ebuf, RowPtr, CsrEid, Albuf);
        agg_kernel<<<NN, 256, 0, stream>>>(Hbuf, Albuf, RowPtr, CsrDst, Resb, xout);
    };

    layer(x,   FXX, W1,  a1s,  a1d,  R1,  X1);
    layer(X1,  FHH, W2,  a2s,  a2d,  R2,  X2);
    layer(dat, FWW, Wd1, ad1s, ad1d, Rd1, D1);
    layer(D1,  FHH, Wd2, ad2s, ad2d, Rd2, D2);

    hipMemsetAsync(Sums, 0, 16, stream);
    pool_reduce<<<dim3(64, 4), 256, 0, stream>>>(X1, X2, D1, D2, Sums);
    att_kernel<<<1, 64, 0, stream>>>(Sums, fc1w, fc1b, fc2w, fc2b, Att);
    final_kernel<<<(NN * 128 + 255) / 256, 256, 0, stream>>>(X1, X2, D1, D2, Att, convw, convb, out);
}

// Round 2
// 626.023 us; speedup vs baseline: 1.3745x; 1.3745x over previous
//
#include <hip/hip_runtime.h>
#include <hip/hip_bf16.h>
#include <math.h>

#define NN 20000
#define EE 320000
#define FXX 256
#define FWW 128
#define FHH 128
#define NH 4

typedef __attribute__((ext_vector_type(8))) short short8v;
typedef __attribute__((ext_vector_type(4))) float f32x4;

// ---------------------------------------------------------------- cast x & dat to bf16
__global__ __launch_bounds__(256) void cast2_kernel(const float* __restrict__ a, __hip_bfloat16* __restrict__ ab, int na,
                                                    const float* __restrict__ b, __hip_bfloat16* __restrict__ bb, int nb)
{
    int i = (blockIdx.x * 256 + threadIdx.x) * 4;
    if (i < na) {
        float4 v = *(const float4*)(a + i);
        ab[i + 0] = __float2bfloat16(v.x); ab[i + 1] = __float2bfloat16(v.y);
        ab[i + 2] = __float2bfloat16(v.z); ab[i + 3] = __float2bfloat16(v.w);
    } else {
        int j = i - na;
        if (j < nb) {
            float4 v = *(const float4*)(b + j);
            bb[j + 0] = __float2bfloat16(v.x); bb[j + 1] = __float2bfloat16(v.y);
            bb[j + 2] = __float2bfloat16(v.z); bb[j + 3] = __float2bfloat16(v.w);
        }
    }
}

// ---------------------------------------------------------------- transpose+cast all weights: src [nm][K][128] -> dst [nm][128][K] bf16
struct TCItem { const float* src; __hip_bfloat16* dst; int K; int total; };
struct TCParams { TCItem t[8]; };

__global__ __launch_bounds__(256) void tcast_all(TCParams p)
{
    TCItem tc = p.t[blockIdx.z];
    int idx = blockIdx.x * 256 + threadIdx.x;
    if (idx >= tc.total) return;
    int per = tc.K << 7;            // K*128
    int mat = idx / per;
    int within = idx - mat * per;
    int k = within >> 7, c = within & 127;
    tc.dst[((size_t)mat * 128 + c) * tc.K + k] = __float2bfloat16(tc.src[idx]);
}

// ---------------------------------------------------------------- MFMA GEMM: C[M,128] = A[M,K] x B[K,128]
// A bf16 row-major [M][K]; Bt bf16 transposed [128][K] (z<4 -> Wtb+z*128*K, z==4 -> Rtb).
// z<4: write bf16 Hb[z]; z==4: write fp32 Resb.
__global__ __launch_bounds__(256) void gat_gemm(const __hip_bfloat16* __restrict__ Ab,
                                                const __hip_bfloat16* __restrict__ Wtb,
                                                const __hip_bfloat16* __restrict__ Rtb,
                                                __hip_bfloat16* __restrict__ Hb,
                                                float* __restrict__ Resb,
                                                int M, int K)
{
    int z = blockIdx.z;
    const __hip_bfloat16* Bt = (z < 4) ? (Wtb + (size_t)z * 128 * K) : Rtb;

    __shared__ short As[128 * 40];   // [row][40] padded, 32 bf16 payload
    __shared__ short Bs[128 * 40];   // [col][40]

    int tid = threadIdx.x;
    int lane = tid & 63, wid = tid >> 6;
    int wr = wid >> 1, wc = wid & 1;
    int ar = lane & 15, kg = lane >> 4;
    int row0 = blockIdx.x * 128;

    f32x4 acc[4][4] = {};

    for (int kb = 0; kb < K; kb += 32) {
        #pragma unroll
        for (int it = 0; it < 2; ++it) {
            int idx = tid + it * 256;
            int row = idx >> 2, seg = idx & 3;
            int grow = row0 + row;
            short8v av = {};
            if (grow < M) av = *(const short8v*)(Ab + (size_t)grow * K + kb + seg * 8);
            *(short8v*)(&As[row * 40 + seg * 8]) = av;
            short8v bv = *(const short8v*)(Bt + (size_t)row * K + kb + seg * 8);
            *(short8v*)(&Bs[row * 40 + seg * 8]) = bv;
        }
        __syncthreads();
        short8v a[4], b[4];
        #pragma unroll
        for (int m = 0; m < 4; ++m)
            a[m] = *(const short8v*)(&As[(wr * 64 + m * 16 + ar) * 40 + kg * 8]);
        #pragma unroll
        for (int n = 0; n < 4; ++n)
            b[n] = *(const short8v*)(&Bs[(wc * 64 + n * 16 + ar) * 40 + kg * 8]);
        #pragma unroll
        for (int m = 0; m < 4; ++m)
            #pragma unroll
            for (int n = 0; n < 4; ++n)
                acc[m][n] = __builtin_amdgcn_mfma_f32_16x16x32_bf16(a[m], b[n], acc[m][n], 0, 0, 0);
        __syncthreads();
    }

    int colb = wc * 64 + (lane & 15);
    int rsub = (lane >> 4) * 4;
    if (z < 4) {
        __hip_bfloat16* Cb = Hb + (size_t)z * NN * 128;
        #pragma unroll
        for (int m = 0; m < 4; ++m)
            #pragma unroll
            for (int r = 0; r < 4; ++r) {
                int row = row0 + wr * 64 + m * 16 + rsub + r;
                if (row < M) {
                    #pragma unroll
                    for (int n = 0; n < 4; ++n)
                        Cb[(size_t)row * 128 + colb + n * 16] = __float2bfloat16(acc[m][n][r]);
                }
            }
    } else {
        #pragma unroll
        for (int m = 0; m < 4; ++m)
            #pragma unroll
            for (int r = 0; r < 4; ++r) {
                int row = row0 + wr * 64 + m * 16 + rsub + r;
                if (row < M) {
                    #pragma unroll
                    for (int n = 0; n < 4; ++n)
                        Resb[(size_t)row * 128 + colb + n * 16] = acc[m][n][r];
                }
            }
    }
}

// ---------------------------------------------------------------- attention scores s_src/s_dst (bf16 h)
__global__ __launch_bounds__(256) void s_kernel(const __hip_bfloat16* __restrict__ Hb,
                                                const float* __restrict__ avs,
                                                const float* __restrict__ avd,
                                                float* __restrict__ ssrc,
                                                float* __restrict__ sdst)
{
    int wid = threadIdx.x >> 6, lane = threadIdx.x & 63;
    int n = blockIdx.x * 4 + wid;
    if (n >= NN) return;
    #pragma unroll
    for (int h = 0; h < NH; ++h) {
        const __hip_bfloat16* hp = Hb + ((size_t)h * NN + n) * 128;
        __hip_bfloat162 hv = *(const __hip_bfloat162*)(hp + 2 * lane);
        float hx = __bfloat162float(hv.x), hy = __bfloat162float(hv.y);
        float2 sv = *(const float2*)(avs + h * 128 + 2 * lane);
        float2 dv = *(const float2*)(avd + h * 128 + 2 * lane);
        float vs = hx * sv.x + hy * sv.y;
        float vd = hx * dv.x + hy * dv.y;
        #pragma unroll
        for (int o = 32; o; o >>= 1) { vs += __shfl_down(vs, o); vd += __shfl_down(vd, o); }
        if (lane == 0) { ssrc[n * 4 + h] = vs; sdst[n * 4 + h] = vd; }
    }
}

// ---------------------------------------------------------------- per-edge scores -> CSR position
__global__ __launch_bounds__(256) void edge_kernel(const int* __restrict__ src,
                                                   const int* __restrict__ dst,
                                                   const int* __restrict__ pos,
                                                   const float* __restrict__ ssrc,
                                                   const float* __restrict__ sdst,
                                                   float* __restrict__ ecsr)
{
    int i = blockIdx.x * blockDim.x + threadIdx.x;
    if (i >= EE) return;
    int s = src[i], d = dst[i];
    float4 a = *(const float4*)(ssrc + (size_t)s * 4);
    float4 b = *(const float4*)(sdst + (size_t)d * 4);
    float4 r; float t;
    t = a.x + b.x; r.x = t >= 0.f ? t : 0.2f * t;
    t = a.y + b.y; r.y = t >= 0.f ? t : 0.2f * t;
    t = a.z + b.z; r.z = t >= 0.f ? t : 0.2f * t;
    t = a.w + b.w; r.w = t >= 0.f ? t : 0.2f * t;
    *(float4*)(ecsr + (size_t)pos[i] * 4) = r;
}

// ---------------------------------------------------------------- CSR build
__global__ __launch_bounds__(256) void hist_kernel(const int* __restrict__ src, int* __restrict__ cnt)
{
    int i = blockIdx.x * blockDim.x + threadIdx.x;
    if (i < EE) atomicAdd(&cnt[src[i]], 1);
}

__global__ __launch_bounds__(1024) void scan_kernel(const int* __restrict__ cnt, int* __restrict__ row_ptr)
{
    __shared__ int lds[1024];
    int t = threadIdx.x;
    const int CH = 20;
    int start = t * CH, end = start + CH; if (end > NN) end = NN;
    int sum = 0;
    if (start < NN) for (int i = start; i < end; ++i) sum += cnt[i];
    lds[t] = sum;
    __syncthreads();
    for (int o = 1; o < 1024; o <<= 1) {
        int v = (t >= o) ? lds[t - o] : 0;
        __syncthreads();
        lds[t] += v;
        __syncthreads();
    }
    int run = lds[t] - sum;
    if (start < NN) for (int i = start; i < end; ++i) { row_ptr[i] = run; run += cnt[i]; }
    if (t == 1023) row_ptr[NN] = lds[1023];
}

__global__ __launch_bounds__(256) void scatter_kernel(const int* __restrict__ src,
                                                      const int* __restrict__ dst,
                                                      const int* __restrict__ row_ptr,
                                                      int* __restrict__ off,
                                                      int* __restrict__ pos,
                                                      int* __restrict__ csr_dst)
{
    int i = blockIdx.x * blockDim.x + threadIdx.x;
    if (i >= EE) return;
    int s = src[i];
    int p = row_ptr[s] + atomicAdd(&off[s], 1);
    pos[i] = p;
    csr_dst[p] = dst[i];
}

// ---------------------------------------------------------------- softmax -> alpha (16-lane groups, sequential ecsr)
__global__ __launch_bounds__(256) void alpha_kernel(const float* __restrict__ ecsr,
                                                    const int* __restrict__ row_ptr,
                                                    float* __restrict__ alpha)
{
    int t = threadIdx.x;
    int g = t >> 4, l = t & 15;
    int n = blockIdx.x * 16 + g;
    if (n >= NN) return;
    int r0 = row_ptr[n], r1 = row_ptr[n + 1];
    int deg = r1 - r0;
    if (deg == 0) return;

    float4 m = make_float4(-1e30f, -1e30f, -1e30f, -1e30f);
    for (int s = l; s < deg; s += 16) {
        float4 ev = *(const float4*)(ecsr + (size_t)(r0 + s) * 4);
        m.x = fmaxf(m.x, ev.x); m.y = fmaxf(m.y, ev.y);
        m.z = fmaxf(m.z, ev.z); m.w = fmaxf(m.w, ev.w);
    }
    #pragma unroll
    for (int o = 8; o; o >>= 1) {
        m.x = fmaxf(m.x, __shfl_xor(m.x, o));
        m.y = fmaxf(m.y, __shfl_xor(m.y, o));
        m.z = fmaxf(m.z, __shfl_xor(m.z, o));
        m.w = fmaxf(m.w, __shfl_xor(m.w, o));
    }
    float4 den = make_float4(0.f, 0.f, 0.f, 0.f);
    for (int s = l; s < deg; s += 16) {
        float4 ev = *(const float4*)(ecsr + (size_t)(r0 + s) * 4);
        den.x += expf(ev.x - m.x); den.y += expf(ev.y - m.y);
        den.z += expf(ev.z - m.z); den.w += expf(ev.w - m.w);
    }
    #pragma unroll
    for (int o = 8; o; o >>= 1) {
        den.x += __shfl_xor(den.x, o); den.y += __shfl_xor(den.y, o);
        den.z += __shfl_xor(den.z, o); den.w += __shfl_xor(den.w, o);
    }
    den.x = 1.f / (den.x + 1e-16f); den.y = 1.f / (den.y + 1e-16f);
    den.z = 1.f / (den.z + 1e-16f); den.w = 1.f / (den.w + 1e-16f);
    for (int s = l; s < deg; s += 16) {
        float4 ev = *(const float4*)(ecsr + (size_t)(r0 + s) * 4);
        float4 o4;
        o4.x = expf(ev.x - m.x) * den.x;
        o4.y = expf(ev.y - m.y) * den.y;
        o4.z = expf(ev.z - m.z) * den.z;
        o4.w = expf(ev.w - m.w) * den.w;
        *(float4*)(alpha + (size_t)(r0 + s) * 4) = o4;
    }
}

// ---------------------------------------------------------------- aggregate + residual + ELU (bf16 h, dual output)
__global__ __launch_bounds__(256) void agg_kernel(const __hip_bfloat16* __restrict__ Hb,
                                                  const float* __restrict__ alpha,
                                                  const int* __restrict__ row_ptr,
                                                  const int* __restrict__ csr_dst,
                                                  const float* __restrict__ res,
                                                  float* __restrict__ xout,
                                                  __hip_bfloat16* __restrict__ xbout)
{
    __shared__ float lds[NH][128];
    int n = blockIdx.x;
    int wid = threadIdx.x >> 6, lane = threadIdx.x & 63;
    int r0 = row_ptr[n], r1 = row_ptr[n + 1];
    const __hip_bfloat16* hbase = Hb + (size_t)wid * NN * 128;
    float2 acc = make_float2(0.f, 0.f);
    for (int s = r0; s < r1; ++s) {
        float w = alpha[(size_t)s * 4 + wid];
        int d = csr_dst[s];
        __hip_bfloat162 hv = *(const __hip_bfloat162*)(hbase + (size_t)d * 128 + 2 * lane);
        acc.x += w * __bfloat162float(hv.x);
        acc.y += w * __bfloat162float(hv.y);
    }
    lds[wid][2 * lane]     = acc.x;
    lds[wid][2 * lane + 1] = acc.y;
    __syncthreads();
    int t = threadIdx.x;
    if (t < 128) {
        float v = (lds[0][t] + lds[1][t] + lds[2][t] + lds[3][t]) * 0.25f
                  + res[(size_t)n * 128 + t];
        v = v > 0.f ? v : expm1f(v);
        xout[(size_t)n * 128 + t] = v;
        xbout[(size_t)n * 128 + t] = __float2bfloat16(v);
    }
}

// ---------------------------------------------------------------- SE pooling
__global__ __launch_bounds__(256) void pool_reduce(const float* __restrict__ x1,
                                                   const float* __restrict__ x2,
                                                   const float* __restrict__ d1,
                                                   const float* __restrict__ d2,
                                                   float* __restrict__ sums)
{
    int c = blockIdx.y;
    const float* p = (c == 0) ? x1 : (c == 1) ? x2 : (c == 2) ? d1 : d2;
    const int total = NN * 128;
    float s = 0.f;
    for (int i = blockIdx.x * blockDim.x + threadIdx.x; i < total; i += gridDim.x * blockDim.x)
        s += p[i];
    #pragma unroll
    for (int o = 32; o; o >>= 1) s += __shfl_down(s, o);
    __shared__ float ls[4];
    if ((threadIdx.x & 63) == 0) ls[threadIdx.x >> 6] = s;
    __syncthreads();
    if (threadIdx.x == 0) atomicAdd(&sums[c], ls[0] + ls[1] + ls[2] + ls[3]);
}

__global__ void att_kernel(const float* __restrict__ sums,
                           const float* __restrict__ fc1w, const float* __restrict__ fc1b,
                           const float* __restrict__ fc2w, const float* __restrict__ fc2b,
                           float* __restrict__ att)
{
    if (threadIdx.x != 0 || blockIdx.x != 0) return;
    float avg[4];
    for (int c = 0; c < 4; ++c) avg[c] = sums[c] * (1.f / (NN * 128.f));
    float z[20];
    for (int j = 0; j < 20; ++j) {
        float v = fc1b[j];
        for (int c = 0; c < 4; ++c) v += avg[c] * fc1w[c * 20 + j];
        z[j] = v;
    }
    for (int c = 0; c < 4; ++c) {
        float v = fc2b[c];
        for (int j = 0; j < 20; ++j) v += z[j] * fc2w[j * 4 + c];
        att[c] = 1.f / (1.f + expf(-v));
    }
}

__global__ __launch_bounds__(256) void final_kernel(const float* __restrict__ x1,
                                                    const float* __restrict__ x2,
                                                    const float* __restrict__ d1,
                                                    const float* __restrict__ d2,
                                                    const float* __restrict__ att,
                                                    const float* __restrict__ convw,
                                                    const float* __restrict__ convb,
                                                    float* __restrict__ out)
{
    int i = blockIdx.x * blockDim.x + threadIdx.x;
    if (i >= NN * 128) return;
    float a0 = att[0], a1 = att[1], a2 = att[2], a3 = att[3];
    float w0 = convw[0], w1 = convw[1], w2 = convw[2], w3 = convw[3];
    float v = convb[0];
    v += w0 * fmaxf(a0 * x1[i], 0.f);
    v += w1 * fmaxf(a1 * x2[i], 0.f);
    v += w2 * fmaxf(a2 * d1[i], 0.f);
    v += w3 * fmaxf(a3 * d2[i], 0.f);
    out[i] = v;
}

// ---------------------------------------------------------------- host
extern "C" void kernel_launch(void* const* d_in, const int* in_sizes, int n_in,
                              void* d_out, int out_size, void* d_ws, size_t ws_size,
                              hipStream_t stream)
{
    (void)in_sizes; (void)n_in; (void)out_size; (void)ws_size;
    const float* x    = (const float*)d_in[0];
    const float* dat  = (const float*)d_in[1];
    const float* W1   = (const float*)d_in[2];
    const float* a1s  = (const float*)d_in[3];
    const float* a1d  = (const float*)d_in[4];
    const float* R1   = (const float*)d_in[5];
    const float* W2   = (const float*)d_in[6];
    const float* a2s  = (const float*)d_in[7];
    const float* a2d  = (const float*)d_in[8];
    const float* R2   = (const float*)d_in[9];
    const float* Wd1  = (const float*)d_in[10];
    const float* ad1s = (const float*)d_in[11];
    const float* ad1d = (const float*)d_in[12];
    const float* Rd1  = (const float*)d_in[13];
    const float* Wd2  = (const float*)d_in[14];
    const float* ad2s = (const float*)d_in[15];
    const float* ad2d = (const float*)d_in[16];
    const float* Rd2  = (const float*)d_in[17];
    const float* fc1w = (const float*)d_in[18];
    const float* fc1b = (const float*)d_in[19];
    const float* fc2w = (const float*)d_in[20];
    const float* fc2b = (const float*)d_in[21];
    const float* convw= (const float*)d_in[22];
    const float* convb= (const float*)d_in[23];
    const int*   eidx = (const int*)d_in[24];
    const int* esrc = eidx;
    const int* edst = eidx + EE;
    float* out = (float*)d_out;

    char* base = (char*)d_ws;
    size_t woff = 0;
    auto alloc = [&](size_t bytes) -> void* {
        void* p = base + woff;
        woff = (woff + bytes + 255) & ~(size_t)255;
        return p;
    };
    __hip_bfloat16* Hb   = (__hip_bfloat16*)alloc((size_t)NH * NN * 128 * 2);
    float* Resb  = (float*)alloc((size_t)NN * 128 * 4);
    float* X1    = (float*)alloc((size_t)NN * 128 * 4);
    float* X2    = (float*)alloc((size_t)NN * 128 * 4);
    float* D1    = (float*)alloc((size_t)NN * 128 * 4);
    float* D2    = (float*)alloc((size_t)NN * 128 * 4);
    __hip_bfloat16* XbX   = (__hip_bfloat16*)alloc((size_t)NN * FXX * 2);
    __hip_bfloat16* XbDat = (__hip_bfloat16*)alloc((size_t)NN * FWW * 2);
    __hip_bfloat16* XbX1  = (__hip_bfloat16*)alloc((size_t)NN * 128 * 2);
    __hip_bfloat16* XbD1  = (__hip_bfloat16*)alloc((size_t)NN * 128 * 2);
    __hip_bfloat16* XbTmp = (__hip_bfloat16*)alloc((size_t)NN * 128 * 2);
    __hip_bfloat16* Wtb1  = (__hip_bfloat16*)alloc((size_t)4 * 128 * FXX * 2);
    __hip_bfloat16* Wtb2  = (__hip_bfloat16*)alloc((size_t)4 * 128 * FHH * 2);
    __hip_bfloat16* Wtd1  = (__hip_bfloat16*)alloc((size_t)4 * 128 * FWW * 2);
    __hip_bfloat16* Wtd2  = (__hip_bfloat16*)alloc((size_t)4 * 128 * FHH * 2);
    __hip_bfloat16* Rtb1  = (__hip_bfloat16*)alloc((size_t)128 * FXX * 2);
    __hip_bfloat16* Rtb2  = (__hip_bfloat16*)alloc((size_t)128 * FHH * 2);
    __hip_bfloat16* Rtd1  = (__hip_bfloat16*)alloc((size_t)128 * FWW * 2);
    __hip_bfloat16* Rtd2  = (__hip_bfloat16*)alloc((size_t)128 * FHH * 2);
    float* Ssrc  = (float*)alloc((size_t)NN * 4 * 4);
    float* Sdst  = (float*)alloc((size_t)NN * 4 * 4);
    float* Ecsr  = (float*)alloc((size_t)EE * 4 * 4);
    float* Albuf = (float*)alloc((size_t)EE * 4 * 4);
    int* RowPtr  = (int*)alloc((size_t)(NN + 1) * 4);
    int* Cnt     = (int*)alloc((size_t)NN * 4);
    int* Off     = (int*)alloc((size_t)NN * 4);
    int* Pos     = (int*)alloc((size_t)EE * 4);
    int* CsrDst  = (int*)alloc((size_t)EE * 4);
    float* Sums  = (float*)alloc(16);
    float* Att   = (float*)alloc(16);

    // input casts + weight transposes
    {
        int na = NN * FXX, nb = NN * FWW;
        cast2_kernel<<<(na + nb + 1023) / 1024, 256, 0, stream>>>(x, XbX, na, dat, XbDat, nb);
        TCParams P;
        P.t[0] = { W1,  Wtb1, FXX, 4 * FXX * 128 };
        P.t[1] = { W2,  Wtb2, FHH, 4 * FHH * 128 };
        P.t[2] = { Wd1, Wtd1, FWW, 4 * FWW * 128 };
        P.t[3] = { Wd2, Wtd2, FHH, 4 * FHH * 128 };
        P.t[4] = { R1,  Rtb1, FXX, FXX * 128 };
        P.t[5] = { R2,  Rtb2, FHH, FHH * 128 };
        P.t[6] = { Rd1, Rtd1, FWW, FWW * 128 };
        P.t[7] = { Rd2, Rtd2, FHH, FHH * 128 };
        tcast_all<<<dim3(512, 1, 8), 256, 0, stream>>>(P);
    }

    // CSR build
    hipMemsetAsync(Cnt, 0, (size_t)NN * 4, stream);
    hipMemsetAsync(Off, 0, (size_t)NN * 4, stream);
    hist_kernel<<<(EE + 255) / 256, 256, 0, stream>>>(esrc, Cnt);
    scan_kernel<<<1, 1024, 0, stream>>>(Cnt, RowPtr);
    scatter_kernel<<<(EE + 255) / 256, 256, 0, stream>>>(esrc, edst, RowPtr, Off, Pos, CsrDst);

    auto layer = [&](const __hip_bfloat16* xb, int K,
                     const __hip_bfloat16* Wtb, const __hip_bfloat16* Rtb,
                     const float* as_, const float* ad_,
                     float* xout, __hip_bfloat16* xbout) {
        dim3 g((NN + 127) / 128, 1, 5);
        gat_gemm<<<g, 256, 0, stream>>>(xb, Wtb, Rtb, Hb, Resb, NN, K);
        s_kernel<<<(NN + 3) / 4, 256, 0, stream>>>(Hb, as_, ad_, Ssrc, Sdst);
        edge_kernel<<<(EE + 255) / 256, 256, 0, stream>>>(esrc, edst, Pos, Ssrc, Sdst, Ecsr);
        alpha_kernel<<<(NN + 15) / 16, 256, 0, stream>>>(Ecsr, RowPtr, Albuf);
        agg_kernel<<<NN, 256, 0, stream>>>(Hb, Albuf, RowPtr, CsrDst, Resb, xout, xbout);
    };

    layer(XbX,   FXX, Wtb1, Rtb1, a1s,  a1d,  X1, XbX1);
    layer(XbX1,  FHH, Wtb2, Rtb2, a2s,  a2d,  X2, XbTmp);
    layer(XbDat, FWW, Wtd1, Rtd1, ad1s, ad1d, D1, XbD1);
    layer(XbD1,  FHH, Wtd2, Rtd2, ad2s, ad2d, D2, XbTmp);

    hipMemsetAsync(Sums, 0, 16, stream);
    pool_reduce<<<dim3(64, 4), 256, 0, stream>>>(X1, X2, D1, D2, Sums);
    att_kernel<<<1, 64, 0, stream>>>(Sums, fc1w, fc1b, fc2w, fc2b, Att);
    final_kernel<<<(NN * 128 + 255) / 256, 256, 0, stream>>>(X1, X2, D1, D2, Att, convw, convb, out);
}

// Round 3
// 466.965 us; speedup vs baseline: 1.8426x; 1.3406x over previous
//
#include <hip/hip_runtime.h>
#include <hip/hip_bf16.h>
#include <math.h>

#define NN 20000
#define EE 320000
#define FXX 256
#define FWW 128
#define FHH 128
#define NH 4

typedef __attribute__((ext_vector_type(8))) short short8v;
typedef __attribute__((ext_vector_type(4))) float f32x4;

__device__ __forceinline__ float bf2f(short s) {
    unsigned int u = ((unsigned int)(unsigned short)s) << 16;
    return __builtin_bit_cast(float, u);
}

// ---------------------------------------------------------------- cast x & dat to bf16
__global__ __launch_bounds__(256) void cast2_kernel(const float* __restrict__ a, __hip_bfloat16* __restrict__ ab, int na,
                                                    const float* __restrict__ b, __hip_bfloat16* __restrict__ bb, int nb)
{
    int i = (blockIdx.x * 256 + threadIdx.x) * 4;
    if (i < na) {
        float4 v = *(const float4*)(a + i);
        ab[i + 0] = __float2bfloat16(v.x); ab[i + 1] = __float2bfloat16(v.y);
        ab[i + 2] = __float2bfloat16(v.z); ab[i + 3] = __float2bfloat16(v.w);
    } else {
        int j = i - na;
        if (j < nb) {
            float4 v = *(const float4*)(b + j);
            bb[j + 0] = __float2bfloat16(v.x); bb[j + 1] = __float2bfloat16(v.y);
            bb[j + 2] = __float2bfloat16(v.z); bb[j + 3] = __float2bfloat16(v.w);
        }
    }
}

// ---------------------------------------------------------------- transpose+cast weights: [nm][K][128] -> [nm][128][K] bf16
struct TCItem { const float* src; __hip_bfloat16* dst; int K; int total; };
struct TCParams { TCItem t[8]; };

__global__ __launch_bounds__(256) void tcast_all(TCParams p)
{
    TCItem tc = p.t[blockIdx.z];
    int idx = blockIdx.x * 256 + threadIdx.x;
    if (idx >= tc.total) return;
    int per = tc.K << 7;
    int mat = idx / per;
    int within = idx - mat * per;
    int k = within >> 7, c = within & 127;
    tc.dst[((size_t)mat * 128 + c) * tc.K + k] = __float2bfloat16(tc.src[idx]);
}

// ---------------------------------------------------------------- MFMA GEMM: C[M,128] = A[M,K] x B[K,128]
// z<4: write bf16 into Hb[node][z*128..] (row stride 512); z==4: fp32 Resb[node][128].
__global__ __launch_bounds__(256) void gat_gemm(const __hip_bfloat16* __restrict__ Ab,
                                                const __hip_bfloat16* __restrict__ Wtb,
                                                const __hip_bfloat16* __restrict__ Rtb,
                                                __hip_bfloat16* __restrict__ Hb,
                                                float* __restrict__ Resb,
                                                int M, int K)
{
    int z = blockIdx.z;
    const __hip_bfloat16* Bt = (z < 4) ? (Wtb + (size_t)z * 128 * K) : Rtb;

    __shared__ short As[128 * 40];
    __shared__ short Bs[128 * 40];

    int tid = threadIdx.x;
    int lane = tid & 63, wid = tid >> 6;
    int wr = wid >> 1, wc = wid & 1;
    int ar = lane & 15, kg = lane >> 4;
    int row0 = blockIdx.x * 128;

    f32x4 acc[4][4] = {};

    for (int kb = 0; kb < K; kb += 32) {
        #pragma unroll
        for (int it = 0; it < 2; ++it) {
            int idx = tid + it * 256;
            int row = idx >> 2, seg = idx & 3;
            int grow = row0 + row;
            short8v av = {};
            if (grow < M) av = *(const short8v*)(Ab + (size_t)grow * K + kb + seg * 8);
            *(short8v*)(&As[row * 40 + seg * 8]) = av;
            short8v bv = *(const short8v*)(Bt + (size_t)row * K + kb + seg * 8);
            *(short8v*)(&Bs[row * 40 + seg * 8]) = bv;
        }
        __syncthreads();
        short8v a[4], b[4];
        #pragma unroll
        for (int m = 0; m < 4; ++m)
            a[m] = *(const short8v*)(&As[(wr * 64 + m * 16 + ar) * 40 + kg * 8]);
        #pragma unroll
        for (int n = 0; n < 4; ++n)
            b[n] = *(const short8v*)(&Bs[(wc * 64 + n * 16 + ar) * 40 + kg * 8]);
        #pragma unroll
        for (int m = 0; m < 4; ++m)
            #pragma unroll
            for (int n = 0; n < 4; ++n)
                acc[m][n] = __builtin_amdgcn_mfma_f32_16x16x32_bf16(a[m], b[n], acc[m][n], 0, 0, 0);
        __syncthreads();
    }

    int colb = wc * 64 + (lane & 15);
    int rsub = (lane >> 4) * 4;
    if (z < 4) {
        __hip_bfloat16* Cb = Hb + (size_t)z * 128;
        #pragma unroll
        for (int m = 0; m < 4; ++m)
            #pragma unroll
            for (int r = 0; r < 4; ++r) {
                int row = row0 + wr * 64 + m * 16 + rsub + r;
                if (row < M) {
                    #pragma unroll
                    for (int n = 0; n < 4; ++n)
                        Cb[(size_t)row * 512 + colb + n * 16] = __float2bfloat16(acc[m][n][r]);
                }
            }
    } else {
        #pragma unroll
        for (int m = 0; m < 4; ++m)
            #pragma unroll
            for (int r = 0; r < 4; ++r) {
                int row = row0 + wr * 64 + m * 16 + rsub + r;
                if (row < M) {
                    #pragma unroll
                    for (int n = 0; n < 4; ++n)
                        Resb[(size_t)row * 128 + colb + n * 16] = acc[m][n][r];
                }
            }
    }
}

// ---------------------------------------------------------------- s_src/s_dst: wave per node, contiguous 1KB row
__global__ __launch_bounds__(256) void s_kernel(const __hip_bfloat16* __restrict__ Hb,
                                                const float* __restrict__ avs,
                                                const float* __restrict__ avd,
                                                float* __restrict__ ssrc,
                                                float* __restrict__ sdst)
{
    int wid = threadIdx.x >> 6, lane = threadIdx.x & 63;
    int n = blockIdx.x * 4 + wid;
    if (n >= NN) return;
    int h = lane >> 4, q = lane & 15;
    short8v hv = *(const short8v*)(Hb + (size_t)n * 512 + lane * 8);
    const float* as_ = avs + h * 128 + q * 8;
    const float* ad_ = avd + h * 128 + q * 8;
    float4 s0 = *(const float4*)(as_), s1 = *(const float4*)(as_ + 4);
    float4 d0 = *(const float4*)(ad_), d1 = *(const float4*)(ad_ + 4);
    float hf[8];
    #pragma unroll
    for (int j = 0; j < 8; ++j) hf[j] = bf2f(hv[j]);
    float vs = hf[0]*s0.x + hf[1]*s0.y + hf[2]*s0.z + hf[3]*s0.w
             + hf[4]*s1.x + hf[5]*s1.y + hf[6]*s1.z + hf[7]*s1.w;
    float vd = hf[0]*d0.x + hf[1]*d0.y + hf[2]*d0.z + hf[3]*d0.w
             + hf[4]*d1.x + hf[5]*d1.y + hf[6]*d1.z + hf[7]*d1.w;
    #pragma unroll
    for (int o = 8; o; o >>= 1) { vs += __shfl_xor(vs, o); vd += __shfl_xor(vd, o); }
    if (q == 0) { ssrc[n * 4 + h] = vs; sdst[n * 4 + h] = vd; }
}

// ---------------------------------------------------------------- CSR build
__global__ __launch_bounds__(256) void hist_kernel(const int* __restrict__ src, int* __restrict__ cnt)
{
    int i = blockIdx.x * blockDim.x + threadIdx.x;
    if (i < EE) atomicAdd(&cnt[src[i]], 1);
}

__global__ __launch_bounds__(1024) void scan_kernel(const int* __restrict__ cnt, int* __restrict__ row_ptr)
{
    __shared__ int lds[1024];
    int t = threadIdx.x;
    const int CH = 20;
    int start = t * CH, end = start + CH; if (end > NN) end = NN;
    int sum = 0;
    if (start < NN) for (int i = start; i < end; ++i) sum += cnt[i];
    lds[t] = sum;
    __syncthreads();
    for (int o = 1; o < 1024; o <<= 1) {
        int v = (t >= o) ? lds[t - o] : 0;
        __syncthreads();
        lds[t] += v;
        __syncthreads();
    }
    int run = lds[t] - sum;
    if (start < NN) for (int i = start; i < end; ++i) { row_ptr[i] = run; run += cnt[i]; }
    if (t == 1023) row_ptr[NN] = lds[1023];
}

__global__ __launch_bounds__(256) void scatter_kernel(const int* __restrict__ src,
                                                      const int* __restrict__ dst,
                                                      const int* __restrict__ row_ptr,
                                                      int* __restrict__ off,
                                                      int* __restrict__ csr_dst)
{
    int i = blockIdx.x * blockDim.x + threadIdx.x;
    if (i >= EE) return;
    int s = src[i];
    int p = row_ptr[s] + atomicAdd(&off[s], 1);
    csr_dst[p] = dst[i];
}

// ---------------------------------------------------------------- fused edge-score + softmax (16-lane groups)
__global__ __launch_bounds__(256) void alpha_kernel(const float* __restrict__ ssrc,
                                                    const float* __restrict__ sdst,
                                                    const int* __restrict__ row_ptr,
                                                    const int* __restrict__ csr_dst,
                                                    float* __restrict__ ecsr,
                                                    float* __restrict__ alpha)
{
    int t = threadIdx.x;
    int g = t >> 4, l = t & 15;
    int n = blockIdx.x * 16 + g;
    if (n >= NN) return;
    int r0 = row_ptr[n], r1 = row_ptr[n + 1];
    int deg = r1 - r0;
    if (deg == 0) return;

    float4 sn = *(const float4*)(ssrc + (size_t)n * 4);
    float4 m = make_float4(-1e30f, -1e30f, -1e30f, -1e30f);
    for (int s = l; s < deg; s += 16) {
        int d = csr_dst[r0 + s];
        float4 sd = *(const float4*)(sdst + (size_t)d * 4);
        float4 e; float v;
        v = sn.x + sd.x; e.x = v >= 0.f ? v : 0.2f * v;
        v = sn.y + sd.y; e.y = v >= 0.f ? v : 0.2f * v;
        v = sn.z + sd.z; e.z = v >= 0.f ? v : 0.2f * v;
        v = sn.w + sd.w; e.w = v >= 0.f ? v : 0.2f * v;
        *(float4*)(ecsr + (size_t)(r0 + s) * 4) = e;
        m.x = fmaxf(m.x, e.x); m.y = fmaxf(m.y, e.y);
        m.z = fmaxf(m.z, e.z); m.w = fmaxf(m.w, e.w);
    }
    #pragma unroll
    for (int o = 8; o; o >>= 1) {
        m.x = fmaxf(m.x, __shfl_xor(m.x, o));
        m.y = fmaxf(m.y, __shfl_xor(m.y, o));
        m.z = fmaxf(m.z, __shfl_xor(m.z, o));
        m.w = fmaxf(m.w, __shfl_xor(m.w, o));
    }
    float4 den = make_float4(0.f, 0.f, 0.f, 0.f);
    for (int s = l; s < deg; s += 16) {
        float4 ev = *(const float4*)(ecsr + (size_t)(r0 + s) * 4);
        ev.x = expf(ev.x - m.x); ev.y = expf(ev.y - m.y);
        ev.z = expf(ev.z - m.z); ev.w = expf(ev.w - m.w);
        *(float4*)(ecsr + (size_t)(r0 + s) * 4) = ev;
        den.x += ev.x; den.y += ev.y; den.z += ev.z; den.w += ev.w;
    }
    #pragma unroll
    for (int o = 8; o; o >>= 1) {
        den.x += __shfl_xor(den.x, o); den.y += __shfl_xor(den.y, o);
        den.z += __shfl_xor(den.z, o); den.w += __shfl_xor(den.w, o);
    }
    den.x = 1.f / (den.x + 1e-16f); den.y = 1.f / (den.y + 1e-16f);
    den.z = 1.f / (den.z + 1e-16f); den.w = 1.f / (den.w + 1e-16f);
    for (int s = l; s < deg; s += 16) {
        float4 ev = *(const float4*)(ecsr + (size_t)(r0 + s) * 4);
        ev.x *= den.x; ev.y *= den.y; ev.z *= den.z; ev.w *= den.w;
        *(float4*)(alpha + (size_t)(r0 + s) * 4) = ev;
    }
}

// ---------------------------------------------------------------- aggregate: 4 waves x edge-parallel, 1KB contiguous gather
__global__ __launch_bounds__(256) void agg_kernel(const __hip_bfloat16* __restrict__ Hb,   // [N][512]
                                                  const float* __restrict__ alpha,
                                                  const int* __restrict__ row_ptr,
                                                  const int* __restrict__ csr_dst,
                                                  const float* __restrict__ res,
                                                  float* __restrict__ xout,
                                                  __hip_bfloat16* __restrict__ xbout)
{
    __shared__ float lds[4][128];
    int n = blockIdx.x;
    int wid = threadIdx.x >> 6, lane = threadIdx.x & 63;
    int h = lane >> 4, q = lane & 15;
    int r0 = row_ptr[n], r1 = row_ptr[n + 1];
    float acc[8] = {};
    for (int p = r0 + wid; p < r1; p += 4) {
        int d = csr_dst[p];
        float a = alpha[(size_t)p * 4 + h];
        short8v hv = *(const short8v*)(Hb + (size_t)d * 512 + lane * 8);
        #pragma unroll
        for (int j = 0; j < 8; ++j) acc[j] += a * bf2f(hv[j]);
    }
    #pragma unroll
    for (int j = 0; j < 8; ++j) acc[j] += __shfl_xor(acc[j], 32);
    #pragma unroll
    for (int j = 0; j < 8; ++j) acc[j] += __shfl_xor(acc[j], 16);
    if (lane < 16) {
        #pragma unroll
        for (int j = 0; j < 8; ++j) lds[wid][q * 8 + j] = acc[j];
    }
    __syncthreads();
    int t = threadIdx.x;
    if (t < 128) {
        float v = (lds[0][t] + lds[1][t] + lds[2][t] + lds[3][t]) * 0.25f
                  + res[(size_t)n * 128 + t];
        v = v > 0.f ? v : expm1f(v);
        xout[(size_t)n * 128 + t] = v;
        xbout[(size_t)n * 128 + t] = __float2bfloat16(v);
    }
}

// ---------------------------------------------------------------- SE pooling
__global__ __launch_bounds__(256) void pool_reduce(const float* __restrict__ x1,
                                                   const float* __restrict__ x2,
                                                   const float* __restrict__ d1,
                                                   const float* __restrict__ d2,
                                                   float* __restrict__ sums)
{
    int c = blockIdx.y;
    const float* p = (c == 0) ? x1 : (c == 1) ? x2 : (c == 2) ? d1 : d2;
    const int total = NN * 128;
    float s = 0.f;
    for (int i = blockIdx.x * blockDim.x + threadIdx.x; i < total; i += gridDim.x * blockDim.x)
        s += p[i];
    #pragma unroll
    for (int o = 32; o; o >>= 1) s += __shfl_down(s, o);
    __shared__ float ls[4];
    if ((threadIdx.x & 63) == 0) ls[threadIdx.x >> 6] = s;
    __syncthreads();
    if (threadIdx.x == 0) atomicAdd(&sums[c], ls[0] + ls[1] + ls[2] + ls[3]);
}

__global__ void att_kernel(const float* __restrict__ sums,
                           const float* __restrict__ fc1w, const float* __restrict__ fc1b,
                           const float* __restrict__ fc2w, const float* __restrict__ fc2b,
                           float* __restrict__ att)
{
    if (threadIdx.x != 0 || blockIdx.x != 0) return;
    float avg[4];
    for (int c = 0; c < 4; ++c) avg[c] = sums[c] * (1.f / (NN * 128.f));
    float z[20];
    for (int j = 0; j < 20; ++j) {
        float v = fc1b[j];
        for (int c = 0; c < 4; ++c) v += avg[c] * fc1w[c * 20 + j];
        z[j] = v;
    }
    for (int c = 0; c < 4; ++c) {
        float v = fc2b[c];
        for (int j = 0; j < 20; ++j) v += z[j] * fc2w[j * 4 + c];
        att[c] = 1.f / (1.f + expf(-v));
    }
}

__global__ __launch_bounds__(256) void final_kernel(const float* __restrict__ x1,
                                                    const float* __restrict__ x2,
                                                    const float* __restrict__ d1,
                                                    const float* __restrict__ d2,
                                                    const float* __restrict__ att,
                                                    const float* __restrict__ convw,
                                                    const float* __restrict__ convb,
                                                    float* __restrict__ out)
{
    int i = blockIdx.x * blockDim.x + threadIdx.x;
    if (i >= NN * 128) return;
    float a0 = att[0], a1 = att[1], a2 = att[2], a3 = att[3];
    float w0 = convw[0], w1 = convw[1], w2 = convw[2], w3 = convw[3];
    float v = convb[0];
    v += w0 * fmaxf(a0 * x1[i], 0.f);
    v += w1 * fmaxf(a1 * x2[i], 0.f);
    v += w2 * fmaxf(a2 * d1[i], 0.f);
    v += w3 * fmaxf(a3 * d2[i], 0.f);
    out[i] = v;
}

// ---------------------------------------------------------------- host
extern "C" void kernel_launch(void* const* d_in, const int* in_sizes, int n_in,
                              void* d_out, int out_size, void* d_ws, size_t ws_size,
                              hipStream_t stream)
{
    (void)in_sizes; (void)n_in; (void)out_size; (void)ws_size;
    const float* x    = (const float*)d_in[0];
    const float* dat  = (const float*)d_in[1];
    const float* W1   = (const float*)d_in[2];
    const float* a1s  = (const float*)d_in[3];
    const float* a1d  = (const float*)d_in[4];
    const float* R1   = (const float*)d_in[5];
    const float* W2   = (const float*)d_in[6];
    const float* a2s  = (const float*)d_in[7];
    const float* a2d  = (const float*)d_in[8];
    const float* R2   = (const float*)d_in[9];
    const float* Wd1  = (const float*)d_in[10];
    const float* ad1s = (const float*)d_in[11];
    const float* ad1d = (const float*)d_in[12];
    const float* Rd1  = (const float*)d_in[13];
    const float* Wd2  = (const float*)d_in[14];
    const float* ad2s = (const float*)d_in[15];
    const float* ad2d = (const float*)d_in[16];
    const float* Rd2  = (const float*)d_in[17];
    const float* fc1w = (const float*)d_in[18];
    const float* fc1b = (const float*)d_in[19];
    const float* fc2w = (const float*)d_in[20];
    const float* fc2b = (const float*)d_in[21];
    const float* convw= (const float*)d_in[22];
    const float* convb= (const float*)d_in[23];
    const int*   eidx = (const int*)d_in[24];
    const int* esrc = eidx;
    const int* edst = eidx + EE;
    float* out = (float*)d_out;

    char* base = (char*)d_ws;
    size_t woff = 0;
    auto alloc = [&](size_t bytes) -> void* {
        void* p = base + woff;
        woff = (woff + bytes + 255) & ~(size_t)255;
        return p;
    };
    __hip_bfloat16* Hb   = (__hip_bfloat16*)alloc((size_t)NN * 512 * 2);
    float* Resb  = (float*)alloc((size_t)NN * 128 * 4);
    float* X1    = (float*)alloc((size_t)NN * 128 * 4);
    float* X2    = (float*)alloc((size_t)NN * 128 * 4);
    float* D1    = (float*)alloc((size_t)NN * 128 * 4);
    float* D2    = (float*)alloc((size_t)NN * 128 * 4);
    __hip_bfloat16* XbX   = (__hip_bfloat16*)alloc((size_t)NN * FXX * 2);
    __hip_bfloat16* XbDat = (__hip_bfloat16*)alloc((size_t)NN * FWW * 2);
    __hip_bfloat16* XbX1  = (__hip_bfloat16*)alloc((size_t)NN * 128 * 2);
    __hip_bfloat16* XbD1  = (__hip_bfloat16*)alloc((size_t)NN * 128 * 2);
    __hip_bfloat16* XbTmp = (__hip_bfloat16*)alloc((size_t)NN * 128 * 2);
    __hip_bfloat16* Wtb1  = (__hip_bfloat16*)alloc((size_t)4 * 128 * FXX * 2);
    __hip_bfloat16* Wtb2  = (__hip_bfloat16*)alloc((size_t)4 * 128 * FHH * 2);
    __hip_bfloat16* Wtd1  = (__hip_bfloat16*)alloc((size_t)4 * 128 * FWW * 2);
    __hip_bfloat16* Wtd2  = (__hip_bfloat16*)alloc((size_t)4 * 128 * FHH * 2);
    __hip_bfloat16* Rtb1  = (__hip_bfloat16*)alloc((size_t)128 * FXX * 2);
    __hip_bfloat16* Rtb2  = (__hip_bfloat16*)alloc((size_t)128 * FHH * 2);
    __hip_bfloat16* Rtd1  = (__hip_bfloat16*)alloc((size_t)128 * FWW * 2);
    __hip_bfloat16* Rtd2  = (__hip_bfloat16*)alloc((size_t)128 * FHH * 2);
    float* Ssrc  = (float*)alloc((size_t)NN * 4 * 4);
    float* Sdst  = (float*)alloc((size_t)NN * 4 * 4);
    float* Ecsr  = (float*)alloc((size_t)EE * 4 * 4);
    float* Albuf = (float*)alloc((size_t)EE * 4 * 4);
    int* RowPtr  = (int*)alloc((size_t)(NN + 1) * 4);
    int* Cnt     = (int*)alloc((size_t)NN * 4);
    int* Off     = (int*)alloc((size_t)NN * 4);
    int* CsrDst  = (int*)alloc((size_t)EE * 4);
    float* Sums  = (float*)alloc(16);
    float* Att   = (float*)alloc(16);

    {
        int na = NN * FXX, nb = NN * FWW;
        cast2_kernel<<<(na + nb + 1023) / 1024, 256, 0, stream>>>(x, XbX, na, dat, XbDat, nb);
        TCParams P;
        P.t[0] = { W1,  Wtb1, FXX, 4 * FXX * 128 };
        P.t[1] = { W2,  Wtb2, FHH, 4 * FHH * 128 };
        P.t[2] = { Wd1, Wtd1, FWW, 4 * FWW * 128 };
        P.t[3] = { Wd2, Wtd2, FHH, 4 * FHH * 128 };
        P.t[4] = { R1,  Rtb1, FXX, FXX * 128 };
        P.t[5] = { R2,  Rtb2, FHH, FHH * 128 };
        P.t[6] = { Rd1, Rtd1, FWW, FWW * 128 };
        P.t[7] = { Rd2, Rtd2, FHH, FHH * 128 };
        tcast_all<<<dim3(512, 1, 8), 256, 0, stream>>>(P);
    }

    hipMemsetAsync(Cnt, 0, (size_t)NN * 4, stream);
    hipMemsetAsync(Off, 0, (size_t)NN * 4, stream);
    hist_kernel<<<(EE + 255) / 256, 256, 0, stream>>>(esrc, Cnt);
    scan_kernel<<<1, 1024, 0, stream>>>(Cnt, RowPtr);
    scatter_kernel<<<(EE + 255) / 256, 256, 0, stream>>>(esrc, edst, RowPtr, Off, CsrDst);

    auto layer = [&](const __hip_bfloat16* xb, int K,
                     const __hip_bfloat16* Wtb, const __hip_bfloat16* Rtb,
                     const float* as_, const float* ad_,
                     float* xout, __hip_bfloat16* xbout) {
        dim3 g((NN + 127) / 128, 1, 5);
        gat_gemm<<<g, 256, 0, stream>>>(xb, Wtb, Rtb, Hb, Resb, NN, K);
        s_kernel<<<(NN + 3) / 4, 256, 0, stream>>>(Hb, as_, ad_, Ssrc, Sdst);
        alpha_kernel<<<(NN + 15) / 16, 256, 0, stream>>>(Ssrc, Sdst, RowPtr, CsrDst, Ecsr, Albuf);
        agg_kernel<<<NN, 256, 0, stream>>>(Hb, Albuf, RowPtr, CsrDst, Resb, xout, xbout);
    };

    layer(XbX,   FXX, Wtb1, Rtb1, a1s,  a1d,  X1, XbX1);
    layer(XbX1,  FHH, Wtb2, Rtb2, a2s,  a2d,  X2, XbTmp);
    layer(XbDat, FWW, Wtd1, Rtd1, ad1s, ad1d, D1, XbD1);
    layer(XbD1,  FHH, Wtd2, Rtd2, ad2s, ad2d, D2, XbTmp);

    hipMemsetAsync(Sums, 0, 16, stream);
    pool_reduce<<<dim3(64, 4), 256, 0, stream>>>(X1, X2, D1, D2, Sums);
    att_kernel<<<1, 64, 0, stream>>>(Sums, fc1w, fc1b, fc2w, fc2b, Att);
    final_kernel<<<(NN * 128 + 255) / 256, 256, 0, stream>>>(X1, X2, D1, D2, Att, convw, convb, out);
}

// Round 5
// 433.493 us; speedup vs baseline: 1.9849x; 1.0772x over previous
//
#include <hip/hip_runtime.h>
#include <hip/hip_bf16.h>
#include <math.h>

#define NN 20000
#define EE 320000
#define FXX 256
#define FWW 128
#define NH 4

typedef __attribute__((ext_vector_type(8))) short short8v;
typedef __attribute__((ext_vector_type(4))) float f32x4;

static __device__ __forceinline__ float bf2f(unsigned short s) {
    unsigned int u = ((unsigned int)s) << 16;
    return __builtin_bit_cast(float, u);
}

// round-to-nearest-even fp32 -> bf16 bits
static __device__ __forceinline__ unsigned short f2bf_u16(float f) {
    unsigned int u = __builtin_bit_cast(unsigned int, f);
    unsigned int r = 0x7fffu + ((u >> 16) & 1u);
    return (unsigned short)((u + r) >> 16);
}

// ---------------------------------------------------------------- cast x & dat to bf16
__global__ __launch_bounds__(256) void cast2_kernel(const float* __restrict__ a, __hip_bfloat16* __restrict__ ab, int na,
                                                    const float* __restrict__ b, __hip_bfloat16* __restrict__ bb, int nb)
{
    int i = (blockIdx.x * 256 + threadIdx.x) * 4;
    if (i < na) {
        float4 v = *(const float4*)(a + i);
        ab[i + 0] = __float2bfloat16(v.x); ab[i + 1] = __float2bfloat16(v.y);
        ab[i + 2] = __float2bfloat16(v.z); ab[i + 3] = __float2bfloat16(v.w);
    } else {
        int j = i - na;
        if (j < nb) {
            float4 v = *(const float4*)(b + j);
            bb[j + 0] = __float2bfloat16(v.x); bb[j + 1] = __float2bfloat16(v.y);
            bb[j + 2] = __float2bfloat16(v.z); bb[j + 3] = __float2bfloat16(v.w);
        }
    }
}

// ---------------------------------------------------------------- w~ = W_h @ a (score projection vectors), fp32
// Wsc layout: [layer][8][256] (stride 256), entries [sd*4+h][k], k in [0,Fin)
struct WscItem { const float* W; const float* as_; const float* ad_; int Fin; };
struct WscParams { WscItem t[4]; };

__global__ __launch_bounds__(256) void wsc_kernel(WscParams p, float* __restrict__ wsc)
{
    int L = blockIdx.z;
    WscItem it = p.t[L];
    int wid = threadIdx.x >> 6, lane = threadIdx.x & 63;
    int r = blockIdx.x * 4 + wid;
    if (r >= it.Fin * 4) return;
    int h = r / it.Fin, k = r - h * it.Fin;
    float2 w2 = *(const float2*)(it.W + ((size_t)(h * it.Fin + k)) * 128 + 2 * lane);
    float2 s2 = *(const float2*)(it.as_ + h * 128 + 2 * lane);
    float2 d2 = *(const float2*)(it.ad_ + h * 128 + 2 * lane);
    float vs = w2.x * s2.x + w2.y * s2.y;
    float vd = w2.x * d2.x + w2.y * d2.y;
    #pragma unroll
    for (int o = 32; o; o >>= 1) { vs += __shfl_xor(vs, o); vd += __shfl_xor(vd, o); }
    if (lane == 0) {
        wsc[(size_t)L * 2048 + h * 256 + k] = vs;
        wsc[(size_t)L * 2048 + (4 + h) * 256 + k] = vd;
    }
}

// ---------------------------------------------------------------- combined GEMM weights: [0.25*W_0;..;0.25*W_3;R] transposed -> [128][KK] bf16
struct WcItem { const float* W; const float* R; __hip_bfloat16* dst; int Fin; int KK; int total; };
struct WcParams { WcItem t[4]; };

__global__ __launch_bounds__(256) void wcomb_kernel(WcParams p)
{
    WcItem it = p.t[blockIdx.z];
    int idx = blockIdx.x * 256 + threadIdx.x;
    if (idx >= it.total) return;     // total = 128*KK
    int c = idx / it.KK;
    int k5 = idx - c * it.KK;
    int f4 = it.Fin * 4;
    float v;
    if (k5 < f4) {
        int h = k5 / it.Fin, k = k5 - h * it.Fin;
        v = 0.25f * it.W[((size_t)(h * it.Fin + k)) * 128 + c];
    } else {
        v = it.R[(size_t)(k5 - f4) * 128 + c];
    }
    it.dst[(size_t)c * it.KK + k5] = __float2bfloat16(v);
}

// ---------------------------------------------------------------- scores: s[n][j] = X[n] . w~[j], wave per node
template<int CF>
__global__ __launch_bounds__(256) void score_kernel(const __hip_bfloat16* __restrict__ Xb,
                                                    const float* __restrict__ wsc,   // [8][256]
                                                    float* __restrict__ ssrc,
                                                    float* __restrict__ sdst)
{
    const int Fin = CF * 64;
    int wid = threadIdx.x >> 6, lane = threadIdx.x & 63;
    int n = blockIdx.x * 4 + wid;
    if (n >= NN) return;
    int c0 = lane * CF;
    union { unsigned u[CF / 2]; unsigned short s[CF]; } ld;
    #pragma unroll
    for (int w = 0; w < CF / 2; ++w)
        ld.u[w] = *(const unsigned*)(Xb + (size_t)n * Fin + c0 + w * 2);
    float xv[CF];
    #pragma unroll
    for (int i = 0; i < CF; ++i) xv[i] = bf2f(ld.s[i]);
    float acc[8];
    #pragma unroll
    for (int j = 0; j < 8; ++j) {
        const float* w = wsc + j * 256 + c0;
        float s = 0.f;
        #pragma unroll
        for (int i = 0; i < CF; ++i) s += xv[i] * w[i];
        acc[j] = s;
    }
    #pragma unroll
    for (int o = 32; o; o >>= 1)
        #pragma unroll
        for (int j = 0; j < 8; ++j) acc[j] += __shfl_xor(acc[j], o);
    if (lane == 0) {
        *(float4*)(ssrc + (size_t)n * 4) = make_float4(acc[0], acc[1], acc[2], acc[3]);
        *(float4*)(sdst + (size_t)n * 4) = make_float4(acc[4], acc[5], acc[6], acc[7]);
    }
}

// ---------------------------------------------------------------- CSR build
__global__ __launch_bounds__(256) void hist_kernel(const int* __restrict__ src, int* __restrict__ cnt)
{
    int i = blockIdx.x * blockDim.x + threadIdx.x;
    if (i < EE) atomicAdd(&cnt[src[i]], 1);
}

__global__ __launch_bounds__(1024) void scan_kernel(const int* __restrict__ cnt, int* __restrict__ row_ptr)
{
    __shared__ int lds[1024];
    int t = threadIdx.x;
    const int CH = 20;
    int start = t * CH, end = start + CH; if (end > NN) end = NN;
    int sum = 0;
    if (start < NN) for (int i = start; i < end; ++i) sum += cnt[i];
    lds[t] = sum;
    __syncthreads();
    for (int o = 1; o < 1024; o <<= 1) {
        int v = (t >= o) ? lds[t - o] : 0;
        __syncthreads();
        lds[t] += v;
        __syncthreads();
    }
    int run = lds[t] - sum;
    if (start < NN) for (int i = start; i < end; ++i) { row_ptr[i] = run; run += cnt[i]; }
    if (t == 1023) row_ptr[NN] = lds[1023];
}

__global__ __launch_bounds__(256) void scatter_kernel(const int* __restrict__ src,
                                                      const int* __restrict__ dst,
                                                      const int* __restrict__ row_ptr,
                                                      int* __restrict__ off,
                                                      int* __restrict__ csr_dst)
{
    int i = blockIdx.x * blockDim.x + threadIdx.x;
    if (i >= EE) return;
    int s = src[i];
    int p = row_ptr[s] + atomicAdd(&off[s], 1);
    csr_dst[p] = dst[i];
}

// ---------------------------------------------------------------- fused edge-score + softmax, scores in registers
__global__ __launch_bounds__(256) void alpha_kernel(const float* __restrict__ ssrc,
                                                    const float* __restrict__ sdst,
                                                    const int* __restrict__ row_ptr,
                                                    const int* __restrict__ csr_dst,
                                                    float* __restrict__ alpha)
{
    int t = threadIdx.x;
    int g = t >> 4, l = t & 15;
    int n = blockIdx.x * 16 + g;
    if (n >= NN) return;
    int r0 = row_ptr[n], r1 = row_ptr[n + 1];
    int deg = r1 - r0;
    if (deg == 0) return;

    float4 sn = *(const float4*)(ssrc + (size_t)n * 4);
    auto comp_e = [&](int s) -> float4 {
        int d = csr_dst[r0 + s];
        float4 sd = *(const float4*)(sdst + (size_t)d * 4);
        float4 e; float v;
        v = sn.x + sd.x; e.x = v >= 0.f ? v : 0.2f * v;
        v = sn.y + sd.y; e.y = v >= 0.f ? v : 0.2f * v;
        v = sn.z + sd.z; e.z = v >= 0.f ? v : 0.2f * v;
        v = sn.w + sd.w; e.w = v >= 0.f ? v : 0.2f * v;
        return e;
    };

    float4 e[8];
    float4 m = make_float4(-1e30f, -1e30f, -1e30f, -1e30f);
    for (int s = l; s < deg; s += 16) {
        float4 ev = comp_e(s);
        int c = s >> 4;
        if (c < 8) e[c] = ev;
        m.x = fmaxf(m.x, ev.x); m.y = fmaxf(m.y, ev.y);
        m.z = fmaxf(m.z, ev.z); m.w = fmaxf(m.w, ev.w);
    }
    #pragma unroll
    for (int o = 8; o; o >>= 1) {
        m.x = fmaxf(m.x, __shfl_xor(m.x, o));
        m.y = fmaxf(m.y, __shfl_xor(m.y, o));
        m.z = fmaxf(m.z, __shfl_xor(m.z, o));
        m.w = fmaxf(m.w, __shfl_xor(m.w, o));
    }
    float4 den = make_float4(0.f, 0.f, 0.f, 0.f);
    for (int s = l; s < deg; s += 16) {
        int c = s >> 4;
        float4 ev = (c < 8) ? e[c] : comp_e(s);
        ev.x = expf(ev.x - m.x); ev.y = expf(ev.y - m.y);
        ev.z = expf(ev.z - m.z); ev.w = expf(ev.w - m.w);
        if (c < 8) e[c] = ev;
        den.x += ev.x; den.y += ev.y; den.z += ev.z; den.w += ev.w;
    }
    #pragma unroll
    for (int o = 8; o; o >>= 1) {
        den.x += __shfl_xor(den.x, o); den.y += __shfl_xor(den.y, o);
        den.z += __shfl_xor(den.z, o); den.w += __shfl_xor(den.w, o);
    }
    den.x = 1.f / (den.x + 1e-16f); den.y = 1.f / (den.y + 1e-16f);
    den.z = 1.f / (den.z + 1e-16f); den.w = 1.f / (den.w + 1e-16f);
    for (int s = l; s < deg; s += 16) {
        int c = s >> 4;
        float4 ev;
        if (c < 8) ev = e[c];
        else {
            ev = comp_e(s);
            ev.x = expf(ev.x - m.x); ev.y = expf(ev.y - m.y);
            ev.z = expf(ev.z - m.z); ev.w = expf(ev.w - m.w);
        }
        ev.x *= den.x; ev.y *= den.y; ev.z *= den.z; ev.w *= den.w;
        *(float4*)(alpha + (size_t)(r0 + s) * 4) = ev;
    }
}

// ---------------------------------------------------------------- aggregate X by head -> Cat = [G0|G1|G2|G3|X], wave per node
template<int CF>
__global__ __launch_bounds__(256) void agg_cat_kernel(const __hip_bfloat16* __restrict__ Xb,   // [N][Fin]
                                                      const float* __restrict__ alpha,
                                                      const int* __restrict__ row_ptr,
                                                      const int* __restrict__ csr_dst,
                                                      __hip_bfloat16* __restrict__ Cat)       // [N][5*Fin]
{
    const int Fin = CF * 64, KK = 5 * Fin;
    int wid = threadIdx.x >> 6, lane = threadIdx.x & 63;
    int n = blockIdx.x * 4 + wid;
    if (n >= NN) return;
    int r0 = row_ptr[n], r1 = row_ptr[n + 1];

    float acc[4][CF] = {};
    for (int r = r0; r < r1; r += 64) {
        int cnt = min(64, r1 - r);
        int d = 0; float4 a4 = make_float4(0.f, 0.f, 0.f, 0.f);
        if (r + lane < r1) {
            d = csr_dst[r + lane];
            a4 = *(const float4*)(alpha + (size_t)(r + lane) * 4);
        }
        for (int j = 0; j < cnt; ++j) {
            int dd = __shfl(d, j);
            float ax = __shfl(a4.x, j), ay = __shfl(a4.y, j);
            float az = __shfl(a4.z, j), aw = __shfl(a4.w, j);
            union { unsigned u[CF / 2]; unsigned short s[CF]; } ld;
            #pragma unroll
            for (int w = 0; w < CF / 2; ++w)
                ld.u[w] = *(const unsigned*)(Xb + (size_t)dd * Fin + lane * CF + w * 2);
            float xv[CF];
            #pragma unroll
            for (int i = 0; i < CF; ++i) xv[i] = bf2f(ld.s[i]);
            #pragma unroll
            for (int i = 0; i < CF; ++i) {
                acc[0][i] += ax * xv[i];
                acc[1][i] += ay * xv[i];
                acc[2][i] += az * xv[i];
                acc[3][i] += aw * xv[i];
            }
        }
    }

    __hip_bfloat16* crow = Cat + (size_t)n * KK;
    #pragma unroll
    for (int h = 0; h < 4; ++h) {
        union { unsigned u[CF / 2]; unsigned short s[CF]; } pk;
        #pragma unroll
        for (int i = 0; i < CF; ++i) pk.s[i] = f2bf_u16(acc[h][i]);
        #pragma unroll
        for (int w = 0; w < CF / 2; ++w)
            *(unsigned*)(crow + h * Fin + lane * CF + w * 2) = pk.u[w];
    }
    // X tail copy
    #pragma unroll
    for (int w = 0; w < CF / 2; ++w)
        *(unsigned*)(crow + 4 * Fin + lane * CF + w * 2) =
            *(const unsigned*)(Xb + (size_t)n * Fin + lane * CF + w * 2);
}

// ---------------------------------------------------------------- MFMA GEMM + ELU epilogue: out[N,128] = Cat[N,KK] x Wct^T
__global__ __launch_bounds__(256) void gemm_elu(const __hip_bfloat16* __restrict__ Cat,
                                                const __hip_bfloat16* __restrict__ Wct,   // [128][KK]
                                                float* __restrict__ xout,
                                                __hip_bfloat16* __restrict__ xbout,
                                                int KK)
{
    __shared__ short As[64 * 40];
    __shared__ short Bs[128 * 40];
    int tid = threadIdx.x, lane = tid & 63, wid = tid >> 6;
    int ar = lane & 15, kg = lane >> 4;
    int row0 = blockIdx.x * 64;

    f32x4 acc[8] = {};

    for (int kb = 0; kb < KK; kb += 32) {
        {
            int row = tid >> 2, seg = tid & 3;
            int grow = row0 + row;
            short8v av = {};
            if (grow < NN) av = *(const short8v*)(Cat + (size_t)grow * KK + kb + seg * 8);
            *(short8v*)(&As[row * 40 + seg * 8]) = av;
        }
        #pragma unroll
        for (int it2 = 0; it2 < 2; ++it2) {
            int idx = tid + it2 * 256;
            int row = idx >> 2, seg = idx & 3;
            short8v bv = *(const short8v*)(Wct + (size_t)row * KK + kb + seg * 8);
            *(short8v*)(&Bs[row * 40 + seg * 8]) = bv;
        }
        __syncthreads();
        short8v a = *(const short8v*)(&As[(wid * 16 + ar) * 40 + kg * 8]);
        #pragma unroll
        for (int nb = 0; nb < 8; ++nb) {
            short8v b = *(const short8v*)(&Bs[(nb * 16 + ar) * 40 + kg * 8]);
            acc[nb] = __builtin_amdgcn_mfma_f32_16x16x32_bf16(a, b, acc[nb], 0, 0, 0);
        }
        __syncthreads();
    }

    int rsub = (lane >> 4) * 4;
    #pragma unroll
    for (int nb = 0; nb < 8; ++nb) {
        int col = nb * 16 + (lane & 15);
        #pragma unroll
        for (int r = 0; r < 4; ++r) {
            int row = row0 + wid * 16 + rsub + r;
            if (row < NN) {
                float v = acc[nb][r];
                v = v > 0.f ? v : expm1f(v);
                xout[(size_t)row * 128 + col] = v;
                xbout[(size_t)row * 128 + col] = __float2bfloat16(v);
            }
        }
    }
}

// ---------------------------------------------------------------- SE pooling
__global__ __launch_bounds__(256) void pool_reduce(const float* __restrict__ x1,
                                                   const float* __restrict__ x2,
                                                   const float* __restrict__ d1,
                                                   const float* __restrict__ d2,
                                                   float* __restrict__ sums)
{
    int c = blockIdx.y;
    const float* p = (c == 0) ? x1 : (c == 1) ? x2 : (c == 2) ? d1 : d2;
    const int total = NN * 128;
    float s = 0.f;
    for (int i = blockIdx.x * blockDim.x + threadIdx.x; i < total; i += gridDim.x * blockDim.x)
        s += p[i];
    #pragma unroll
    for (int o = 32; o; o >>= 1) s += __shfl_down(s, o);
    __shared__ float ls[4];
    if ((threadIdx.x & 63) == 0) ls[threadIdx.x >> 6] = s;
    __syncthreads();
    if (threadIdx.x == 0) atomicAdd(&sums[c], ls[0] + ls[1] + ls[2] + ls[3]);
}

__global__ void att_kernel(const float* __restrict__ sums,
                           const float* __restrict__ fc1w, const float* __restrict__ fc1b,
                           const float* __restrict__ fc2w, const float* __restrict__ fc2b,
                           float* __restrict__ att)
{
    if (threadIdx.x != 0 || blockIdx.x != 0) return;
    float avg[4];
    for (int c = 0; c < 4; ++c) avg[c] = sums[c] * (1.f / (NN * 128.f));
    float z[20];
    for (int j = 0; j < 20; ++j) {
        float v = fc1b[j];
        for (int c = 0; c < 4; ++c) v += avg[c] * fc1w[c * 20 + j];
        z[j] = v;
    }
    for (int c = 0; c < 4; ++c) {
        float v = fc2b[c];
        for (int j = 0; j < 20; ++j) v += z[j] * fc2w[j * 4 + c];
        att[c] = 1.f / (1.f + expf(-v));
    }
}

__global__ __launch_bounds__(256) void final_kernel(const float* __restrict__ x1,
                                                    const float* __restrict__ x2,
                                                    const float* __restrict__ d1,
                                                    const float* __restrict__ d2,
                                                    const float* __restrict__ att,
                                                    const float* __restrict__ convw,
                                                    const float* __restrict__ convb,
                                                    float* __restrict__ out)
{
    int i = blockIdx.x * blockDim.x + threadIdx.x;
    if (i >= NN * 128) return;
    float a0 = att[0], a1 = att[1], a2 = att[2], a3 = att[3];
    float w0 = convw[0], w1 = convw[1], w2 = convw[2], w3 = convw[3];
    float v = convb[0];
    v += w0 * fmaxf(a0 * x1[i], 0.f);
    v += w1 * fmaxf(a1 * x2[i], 0.f);
    v += w2 * fmaxf(a2 * d1[i], 0.f);
    v += w3 * fmaxf(a3 * d2[i], 0.f);
    out[i] = v;
}

// ---------------------------------------------------------------- host
extern "C" void kernel_launch(void* const* d_in, const int* in_sizes, int n_in,
                              void* d_out, int out_size, void* d_ws, size_t ws_size,
                              hipStream_t stream)
{
    (void)in_sizes; (void)n_in; (void)out_size; (void)ws_size;
    const float* x    = (const float*)d_in[0];
    const float* dat  = (const float*)d_in[1];
    const float* W1   = (const float*)d_in[2];
    const float* a1s  = (const float*)d_in[3];
    const float* a1d  = (const float*)d_in[4];
    const float* R1   = (const float*)d_in[5];
    const float* W2   = (const float*)d_in[6];
    const float* a2s  = (const float*)d_in[7];
    const float* a2d  = (const float*)d_in[8];
    const float* R2   = (const float*)d_in[9];
    const float* Wd1  = (const float*)d_in[10];
    const float* ad1s = (const float*)d_in[11];
    const float* ad1d = (const float*)d_in[12];
    const float* Rd1  = (const float*)d_in[13];
    const float* Wd2  = (const float*)d_in[14];
    const float* ad2s = (const float*)d_in[15];
    const float* ad2d = (const float*)d_in[16];
    const float* Rd2  = (const float*)d_in[17];
    const float* fc1w = (const float*)d_in[18];
    const float* fc1b = (const float*)d_in[19];
    const float* fc2w = (const float*)d_in[20];
    const float* fc2b = (const float*)d_in[21];
    const float* convw= (const float*)d_in[22];
    const float* convb= (const float*)d_in[23];
    const int*   eidx = (const int*)d_in[24];
    const int* esrc = eidx;
    const int* edst = eidx + EE;
    float* out = (float*)d_out;

    char* base = (char*)d_ws;
    size_t woff = 0;
    auto alloc = [&](size_t bytes) -> void* {
        void* p = base + woff;
        woff = (woff + bytes + 255) & ~(size_t)255;
        return p;
    };
    __hip_bfloat16* Cat  = (__hip_bfloat16*)alloc((size_t)NN * 1280 * 2);
    float* X1    = (float*)alloc((size_t)NN * 128 * 4);
    float* X2    = (float*)alloc((size_t)NN * 128 * 4);
    float* D1    = (float*)alloc((size_t)NN * 128 * 4);
    float* D2    = (float*)alloc((size_t)NN * 128 * 4);
    __hip_bfloat16* XbX   = (__hip_bfloat16*)alloc((size_t)NN * FXX * 2);
    __hip_bfloat16* XbDat = (__hip_bfloat16*)alloc((size_t)NN * FWW * 2);
    __hip_bfloat16* Xb1   = (__hip_bfloat16*)alloc((size_t)NN * 128 * 2);
    __hip_bfloat16* XbD1  = (__hip_bfloat16*)alloc((size_t)NN * 128 * 2);
    __hip_bfloat16* XbTmp = (__hip_bfloat16*)alloc((size_t)NN * 128 * 2);
    float* Wsc   = (float*)alloc((size_t)4 * 2048 * 4);
    __hip_bfloat16* Wct0 = (__hip_bfloat16*)alloc((size_t)128 * 1280 * 2);
    __hip_bfloat16* Wct1 = (__hip_bfloat16*)alloc((size_t)128 * 640 * 2);
    __hip_bfloat16* Wct2 = (__hip_bfloat16*)alloc((size_t)128 * 640 * 2);
    __hip_bfloat16* Wct3 = (__hip_bfloat16*)alloc((size_t)128 * 640 * 2);
    float* Ssrc  = (float*)alloc((size_t)NN * 4 * 4);
    float* Sdst  = (float*)alloc((size_t)NN * 4 * 4);
    float* Albuf = (float*)alloc((size_t)EE * 4 * 4);
    int* RowPtr  = (int*)alloc((size_t)(NN + 1) * 4);
    int* Cnt     = (int*)alloc((size_t)NN * 4);
    int* Off     = (int*)alloc((size_t)NN * 4);
    int* CsrDst  = (int*)alloc((size_t)EE * 4);
    float* Sums  = (float*)alloc(16);
    float* Att   = (float*)alloc(16);

    // setup: casts, score vectors, combined weights, CSR
    {
        int na = NN * FXX, nb = NN * FWW;
        cast2_kernel<<<(na + nb + 1023) / 1024, 256, 0, stream>>>(x, XbX, na, dat, XbDat, nb);
        WscParams WP;
        WP.t[0] = { W1,  a1s,  a1d,  FXX };
        WP.t[1] = { W2,  a2s,  a2d,  FWW };
        WP.t[2] = { Wd1, ad1s, ad1d, FWW };
        WP.t[3] = { Wd2, ad2s, ad2d, FWW };
        wsc_kernel<<<dim3(256, 1, 4), 256, 0, stream>>>(WP, Wsc);
        WcParams CP;
        CP.t[0] = { W1,  R1,  Wct0, FXX, 1280, 128 * 1280 };
        CP.t[1] = { W2,  R2,  Wct1, FWW, 640,  128 * 640 };
        CP.t[2] = { Wd1, Rd1, Wct2, FWW, 640,  128 * 640 };
        CP.t[3] = { Wd2, Rd2, Wct3, FWW, 640,  128 * 640 };
        wcomb_kernel<<<dim3(640, 1, 4), 256, 0, stream>>>(CP);
    }
    hipMemsetAsync(Cnt, 0, (size_t)NN * 4, stream);
    hipMemsetAsync(Off, 0, (size_t)NN * 4, stream);
    hist_kernel<<<(EE + 255) / 256, 256, 0, stream>>>(esrc, Cnt);
    scan_kernel<<<1, 1024, 0, stream>>>(Cnt, RowPtr);
    scatter_kernel<<<(EE + 255) / 256, 256, 0, stream>>>(esrc, edst, RowPtr, Off, CsrDst);

    auto layer = [&](const __hip_bfloat16* Xb, int CF, int Lidx,
                     const __hip_bfloat16* WctL, float* xout, __hip_bfloat16* xbout) {
        const float* wscL = Wsc + (size_t)Lidx * 2048;
        int KK = 5 * CF * 64;
        if (CF == 4) {
            score_kernel<4><<<(NN + 3) / 4, 256, 0, stream>>>(Xb, wscL, Ssrc, Sdst);
        } else {
            score_kernel<2><<<(NN + 3) / 4, 256, 0, stream>>>(Xb, wscL, Ssrc, Sdst);
        }
        alpha_kernel<<<(NN + 15) / 16, 256, 0, stream>>>(Ssrc, Sdst, RowPtr, CsrDst, Albuf);
        if (CF == 4) {
            agg_cat_kernel<4><<<(NN + 3) / 4, 256, 0, stream>>>(Xb, Albuf, RowPtr, CsrDst, Cat);
        } else {
            agg_cat_kernel<2><<<(NN + 3) / 4, 256, 0, stream>>>(Xb, Albuf, RowPtr, CsrDst, Cat);
        }
        gemm_elu<<<(NN + 63) / 64, 256, 0, stream>>>(Cat, WctL, xout, xbout, KK);
    };

    layer(XbX,   4, 0, Wct0, X1, Xb1);
    layer(Xb1,   2, 1, Wct1, X2, XbTmp);
    layer(XbDat, 2, 2, Wct2, D1, XbD1);
    layer(XbD1,  2, 3, Wct3, D2, XbTmp);

    hipMemsetAsync(Sums, 0, 16, stream);
    pool_reduce<<<dim3(64, 4), 256, 0, stream>>>(X1, X2, D1, D2, Sums);
    att_kernel<<<1, 64, 0, stream>>>(Sums, fc1w, fc1b, fc2w, fc2b, Att);
    final_kernel<<<(NN * 128 + 255) / 256, 256, 0, stream>>>(X1, X2, D1, D2, Att, convw, convb, out);
}